// Round 2
// baseline (121.745 us; speedup 1.0000x reference)
//
#include <hip/hip_runtime.h>

// out = 2 * sum((img1-img2)^2) / N,  N = B*C*H*W  (H==W collapses the
// row-mean + col-mean structure to a single full-tensor mean).
//
// Structure: memset(out,0) graph node + one streaming-reduce kernel.
// Each block reduces to one float and does a single device-scope
// atomicAdd(out, partial*scale). 1024 atomics total -> no contention.

#define BLOCK 256
#define GRID  1024   // 4 blocks/CU; 12 float4-pairs per thread (3 unrolled trips)

__global__ __launch_bounds__(BLOCK) void sq_sum_atomic(
    const float4* __restrict__ a4, const float4* __restrict__ b4,
    long n4, float* __restrict__ out, float scale,
    const float* __restrict__ a, const float* __restrict__ b, long n)
{
    const long T   = (long)gridDim.x * BLOCK;          // total threads
    const long tid = (long)blockIdx.x * BLOCK + threadIdx.x;

    float acc0 = 0.f, acc1 = 0.f, acc2 = 0.f, acc3 = 0.f;

    long i = tid;
    // 4-way unrolled: 8 independent 16B loads in flight per iteration
    for (; i + 3 * T < n4; i += 4 * T) {
        float4 a0 = a4[i];         float4 b0 = b4[i];
        float4 a1 = a4[i + T];     float4 b1 = b4[i + T];
        float4 a2 = a4[i + 2 * T]; float4 b2 = b4[i + 2 * T];
        float4 a3 = a4[i + 3 * T]; float4 b3 = b4[i + 3 * T];
        float d;
        d = a0.x - b0.x; acc0 += d * d;  d = a0.y - b0.y; acc0 += d * d;
        d = a0.z - b0.z; acc0 += d * d;  d = a0.w - b0.w; acc0 += d * d;
        d = a1.x - b1.x; acc1 += d * d;  d = a1.y - b1.y; acc1 += d * d;
        d = a1.z - b1.z; acc1 += d * d;  d = a1.w - b1.w; acc1 += d * d;
        d = a2.x - b2.x; acc2 += d * d;  d = a2.y - b2.y; acc2 += d * d;
        d = a2.z - b2.z; acc2 += d * d;  d = a2.w - b2.w; acc2 += d * d;
        d = a3.x - b3.x; acc3 += d * d;  d = a3.y - b3.y; acc3 += d * d;
        d = a3.z - b3.z; acc3 += d * d;  d = a3.w - b3.w; acc3 += d * d;
    }
    for (; i < n4; i += T) {
        float4 av = a4[i]; float4 bv = b4[i];
        float d;
        d = av.x - bv.x; acc0 += d * d;  d = av.y - bv.y; acc0 += d * d;
        d = av.z - bv.z; acc0 += d * d;  d = av.w - bv.w; acc0 += d * d;
    }
    // scalar tail (n % 4 != 0; not hit for this shape, but safe)
    for (long j = n4 * 4 + tid; j < n; j += T) {
        float d = a[j] - b[j];
        acc0 += d * d;
    }

    float acc = (acc0 + acc1) + (acc2 + acc3);

    // wave64 reduction
    #pragma unroll
    for (int off = 32; off > 0; off >>= 1)
        acc += __shfl_down(acc, off, 64);

    __shared__ float wsum[BLOCK / 64];
    int lane = threadIdx.x & 63;
    int wave = threadIdx.x >> 6;
    if (lane == 0) wsum[wave] = acc;
    __syncthreads();

    if (threadIdx.x == 0) {
        float s = 0.f;
        #pragma unroll
        for (int k = 0; k < BLOCK / 64; ++k) s += wsum[k];
        atomicAdd(out, s * scale);   // device-scope by default on CDNA
    }
}

extern "C" void kernel_launch(void* const* d_in, const int* in_sizes, int n_in,
                              void* d_out, int out_size, void* d_ws, size_t ws_size,
                              hipStream_t stream) {
    const float* a = (const float*)d_in[0];
    const float* b = (const float*)d_in[1];
    float* out = (float*)d_out;
    long n  = (long)in_sizes[0];
    long n4 = n / 4;

    // d_out is poisoned to 0xAA before every timed launch -> zero it ourselves.
    hipMemsetAsync(out, 0, sizeof(float), stream);

    sq_sum_atomic<<<GRID, BLOCK, 0, stream>>>(
        (const float4*)a, (const float4*)b, n4, out, 2.0f / (float)n,
        a, b, n);
}

// Round 3
// 112.337 us; speedup vs baseline: 1.0838x; 1.0838x over previous
//
#include <hip/hip_runtime.h>

// out = 2 * sum((img1-img2)^2) / N,  N = B*C*H*W  (H==W collapses the
// row-mean + col-mean structure to a single full-tensor mean).
//
// Two-stage deterministic reduction (no atomics — 1024 same-address fp32
// atomics serialize at one L2 bank and cost ~8 µs, measured R2).

#define BLOCK 256
#define GRID  1024   // 4 blocks/CU; 12 float4-pairs per thread

__global__ __launch_bounds__(BLOCK) void partial_sq_sum(
    const float4* __restrict__ a4, const float4* __restrict__ b4,
    long n4, float* __restrict__ partials)
{
    const long T   = (long)gridDim.x * BLOCK;
    const long tid = (long)blockIdx.x * BLOCK + threadIdx.x;

    float acc0 = 0.f, acc1 = 0.f;

    long i = tid;
    // 2-way unroll: 4 independent 16B loads in flight per thread
    for (; i + T < n4; i += 2 * T) {
        float4 a0 = a4[i];     float4 b0 = b4[i];
        float4 a1 = a4[i + T]; float4 b1 = b4[i + T];
        float d;
        d = a0.x - b0.x; acc0 += d * d;  d = a0.y - b0.y; acc0 += d * d;
        d = a0.z - b0.z; acc0 += d * d;  d = a0.w - b0.w; acc0 += d * d;
        d = a1.x - b1.x; acc1 += d * d;  d = a1.y - b1.y; acc1 += d * d;
        d = a1.z - b1.z; acc1 += d * d;  d = a1.w - b1.w; acc1 += d * d;
    }
    for (; i < n4; i += T) {
        float4 av = a4[i]; float4 bv = b4[i];
        float d;
        d = av.x - bv.x; acc0 += d * d;  d = av.y - bv.y; acc0 += d * d;
        d = av.z - bv.z; acc0 += d * d;  d = av.w - bv.w; acc0 += d * d;
    }
    float acc = acc0 + acc1;

    // wave64 reduction
    #pragma unroll
    for (int off = 32; off > 0; off >>= 1)
        acc += __shfl_down(acc, off, 64);

    __shared__ float wsum[BLOCK / 64];
    int lane = threadIdx.x & 63;
    int wave = threadIdx.x >> 6;
    if (lane == 0) wsum[wave] = acc;
    __syncthreads();

    if (threadIdx.x == 0) {
        float s = 0.f;
        #pragma unroll
        for (int k = 0; k < BLOCK / 64; ++k) s += wsum[k];
        partials[blockIdx.x] = s;
    }
}

__global__ __launch_bounds__(BLOCK) void final_reduce(
    const float* __restrict__ partials, int nparts,
    const float* __restrict__ a, const float* __restrict__ b,
    long tail_start, long n, float* __restrict__ out, float scale)
{
    float acc = 0.f;
    for (int i = threadIdx.x; i < nparts; i += BLOCK)
        acc += partials[i];

    // scalar tail if n % 4 != 0 (not hit for 16*3*512*512, but safe)
    for (long i = tail_start + threadIdx.x; i < n; i += BLOCK) {
        float d = a[i] - b[i];
        acc += d * d;
    }

    #pragma unroll
    for (int off = 32; off > 0; off >>= 1)
        acc += __shfl_down(acc, off, 64);

    __shared__ float wsum[BLOCK / 64];
    int lane = threadIdx.x & 63;
    int wave = threadIdx.x >> 6;
    if (lane == 0) wsum[wave] = acc;
    __syncthreads();

    if (threadIdx.x == 0) {
        float s = 0.f;
        #pragma unroll
        for (int k = 0; k < BLOCK / 64; ++k) s += wsum[k];
        out[0] = s * scale;
    }
}

extern "C" void kernel_launch(void* const* d_in, const int* in_sizes, int n_in,
                              void* d_out, int out_size, void* d_ws, size_t ws_size,
                              hipStream_t stream) {
    const float* a = (const float*)d_in[0];
    const float* b = (const float*)d_in[1];
    float* out = (float*)d_out;
    long n  = (long)in_sizes[0];
    long n4 = n / 4;

    float* partials = (float*)d_ws;  // GRID floats, deterministically overwritten

    partial_sq_sum<<<GRID, BLOCK, 0, stream>>>(
        (const float4*)a, (const float4*)b, n4, partials);

    final_reduce<<<1, BLOCK, 0, stream>>>(
        partials, GRID, a, b, n4 * 4, n, out, 2.0f / (float)n);
}